// Round 15
// baseline (496.536 us; speedup 1.0000x reference)
//
#include <hip/hip_runtime.h>
#include <math.h>

// GCN: 7 graph-conv layers. N=65536 nodes, E=1048576 edges, feat 128->64(x6)->40.
// dst-CSR once per call (rank co-scheduled with L1 GEMM); 6x fused{pull-
// aggregate (2 nodes/wave, int2 edge meta) + LDS-W float4 GEMM}; final agg.

constexpr int NFEAT = 128, NHID = 64, NCLASS = 40;

typedef unsigned short ushort_t;
typedef int ivec4 __attribute__((ext_vector_type(4)));

__device__ inline ushort_t f2bf(float f) {  // round-to-nearest-even
  union { float f; unsigned int i; } v; v.f = f;
  unsigned int lsb = (v.i >> 16) & 1u;
  v.i += 0x7fffu + lsb;
  return (ushort_t)(v.i >> 16);
}

// Merged: even blocks run the L1 GEMM (S1 = x@W1, 64x64 tile); odd blocks run
// the rank histogram. gemm VALU work fills rank's atomic-latency bubbles.
__global__ __launch_bounds__(256) void rankgemm_k(
    const float* __restrict__ x, const float* __restrict__ W1,
    ushort_t* __restrict__ sout,
    const int* __restrict__ dst, int* __restrict__ cnt4,
    int* __restrict__ rank, int E, int N) {
  constexpr int HS = 68;
  __shared__ float hl[64 * HS];
  __shared__ float wl[64 * 64];
  int tid = threadIdx.x;
  int bid = blockIdx.x;

  if (bid & 1) {
    int i = (bid >> 1) * 256 + tid;
    int base = i * 4;
    if (base >= E) return;
    int4 d4 = *(const int4*)(dst + base);
    int r0 = atomicAdd(&cnt4[0 * N + d4.x], 1);
    int r1 = atomicAdd(&cnt4[1 * N + d4.y], 1);
    int r2 = atomicAdd(&cnt4[2 * N + d4.z], 1);
    int r3 = atomicAdd(&cnt4[3 * N + d4.w], 1);
    ivec4 rr = { (r0 << 2) | 0, (r1 << 2) | 1, (r2 << 2) | 2, (r3 << 2) | 3 };
    __builtin_nontemporal_store(rr, (ivec4*)(rank + base));
    return;
  }

  int row0 = (bid >> 1) * 64;
  int tx = tid & 15, ty = tid >> 4;
  float acc[4][4] = {};
  for (int kc = 0; kc < 128; kc += 64) {
    {
      const float* hb = x + (size_t)row0 * 128 + kc;
      for (int i = tid; i < 64 * 16; i += 256) {
        int r = i >> 4, kk = (i & 15) << 2;
        float4 v = *(const float4*)(hb + (size_t)r * 128 + kk);
        *(float4*)&hl[r * HS + kk] = v;
      }
    }
    {
      const float4* Wb = (const float4*)(W1 + (size_t)kc * 64);
      for (int i = tid; i < 64 * 16; i += 256) ((float4*)wl)[i] = Wb[i];
    }
    __syncthreads();
    for (int k4 = 0; k4 < 64; k4 += 4) {
      float4 a[4];
#pragma unroll
      for (int r = 0; r < 4; ++r)
        a[r] = *(const float4*)&hl[(ty * 4 + r) * HS + k4];
#pragma unroll
      for (int j = 0; j < 4; ++j) {
        float4 bv = *(const float4*)&wl[(k4 + j) * 64 + tx * 4];
        const float* bp = (const float*)&bv;
#pragma unroll
        for (int r = 0; r < 4; ++r) {
          const float* ap = (const float*)&a[r];
#pragma unroll
          for (int c = 0; c < 4; ++c) acc[r][c] += ap[j] * bp[c];
        }
      }
    }
    __syncthreads();
  }
#pragma unroll
  for (int r = 0; r < 4; ++r) {
    ushort_t pk[4];
#pragma unroll
    for (int c = 0; c < 4; ++c) pk[c] = f2bf(acc[r][c]);
    *(ushort4*)&sout[(size_t)(row0 + ty * 4 + r) * 64 + tx * 4] =
        make_ushort4(pk[0], pk[1], pk[2], pk[3]);
  }
}

__global__ void scan1_k(const int* __restrict__ cnt4, int* __restrict__ off,
                        int* __restrict__ bsum, int4* __restrict__ sb4, int n) {
  __shared__ int tmp[256];
  int tid = threadIdx.x;
  int i = blockIdx.x * 256 + tid;
  int c0 = 0, c1 = 0, c2 = 0, c3 = 0;
  if (i < n) {
    c0 = cnt4[i]; c1 = cnt4[n + i]; c2 = cnt4[2 * n + i]; c3 = cnt4[3 * n + i];
  }
  int v = c0 + c1 + c2 + c3;
  tmp[tid] = v;
  __syncthreads();
  for (int d = 1; d < 256; d <<= 1) {
    int t = (tid >= d) ? tmp[tid - d] : 0;
    __syncthreads();
    tmp[tid] += t;
    __syncthreads();
  }
  if (i < n) {
    off[i] = tmp[tid] - v;
    sb4[i] = make_int4(0, c0, c0 + c1, c0 + c1 + c2);
  }
  if (tid == 255) bsum[blockIdx.x] = tmp[255];
}

__global__ void scan2_k(int* __restrict__ bsum, int nb) {
  __shared__ int tmp[256];
  int tid = threadIdx.x;
  int v = (tid < nb) ? bsum[tid] : 0;
  tmp[tid] = v;
  __syncthreads();
  for (int d = 1; d < 256; d <<= 1) {
    int t = (tid >= d) ? tmp[tid - d] : 0;
    __syncthreads();
    tmp[tid] += t;
    __syncthreads();
  }
  if (tid < nb) bsum[tid] = tmp[tid] - v;
}

__global__ void scan3_k(int* __restrict__ off, const int* __restrict__ bsum, int n, int E) {
  int i = blockIdx.x * blockDim.x + threadIdx.x;
  if (i < n) off[i] += bsum[i >> 8];
  if (i == 0) off[n] = E;
}

__global__ void fill_k(const int* __restrict__ src, const int* __restrict__ dst,
                       const float* __restrict__ w, const int* __restrict__ off,
                       const int* __restrict__ rank, const int* __restrict__ sb4,
                       int2* __restrict__ edata, int E) {
  int i = blockIdx.x * blockDim.x + threadIdx.x;
  int base = i * 4;
  if (base >= E) return;
  int4 s4 = *(const int4*)(src + base);
  int4 d4 = *(const int4*)(dst + base);
  float4 w4 = *(const float4*)(w + base);
  int4 r4 = *(const int4*)(rank + base);
  int dd[4] = { d4.x, d4.y, d4.z, d4.w };
  int rr[4] = { r4.x, r4.y, r4.z, r4.w };
  int ss[4] = { s4.x, s4.y, s4.z, s4.w };
  float ww[4] = { w4.x, w4.y, w4.z, w4.w };
  int ob[4], sb[4];
#pragma unroll
  for (int k = 0; k < 4; ++k) ob[k] = off[dd[k]];
#pragma unroll
  for (int k = 0; k < 4; ++k) sb[k] = sb4[dd[k] * 4 + (rr[k] & 3)];
#pragma unroll
  for (int k = 0; k < 4; ++k) {
    int pos = ob[k] + sb[k] + (rr[k] >> 2);
    int2 v = make_int2(ss[k], __float_as_int(ww[k]));
    __builtin_nontemporal_store(*(const long long*)&v, (long long*)&edata[pos]);
  }
}

// Fused pull-aggregate + next-layer GEMM.
// Gather engine (R11-proven): two nodes per wave (A: lanes 0-31, B: 32-63 for
// edge parity; lane owns feature pair 2hl,2hl+1), flat-issue, int2 edge meta
// loaded ONCE per slot (src+weight together).
// GEMM: W[64][64] in LDS (zero-padded for FO=40); within each half lane =
// (s2 = k-half, q = col-quad); float4 W-row reads (broadcast x4 lanes),
// cross-k-half combine via shfl_xor(16); packed uint2 store.
template<int FO, bool WRITE_H>
__global__ __launch_bounds__(256, 4) void aggemm_k(
    const ushort_t* __restrict__ support,   // N x 64 bf16 (layer input S)
    const int2* __restrict__ edata,
    const int* __restrict__ off,
    const float* __restrict__ bias,         // 64
    const float* __restrict__ resid,        // N x 64 f32 or null
    const float* __restrict__ Wn,           // 64 x FO
    ushort_t* __restrict__ sout,            // N x FO bf16 (next layer S)
    float* __restrict__ hout,               // N x 64 f32 (if WRITE_H)
    int n) {
  __shared__ float Wl[64 * 64];
  __shared__ float hls[4][2][64];
  int tid = threadIdx.x;
  if (FO == 64) {
    for (int i = tid; i < 64 * 16; i += 256)
      ((float4*)Wl)[i] = ((const float4*)Wn)[i];
  } else {
    for (int i = tid; i < 64 * 64; i += 256) Wl[i] = 0.0f;
    __syncthreads();
    for (int i = tid; i < 64 * FO; i += 256)
      Wl[(i / FO) * 64 + (i % FO)] = Wn[i];
  }
  __syncthreads();

  int p = (blockIdx.x * blockDim.x + tid) >> 6, lane = tid & 63;
  int wv = tid >> 6;
  int nA = 2 * p, nB = 2 * p + 1;
  if (nA >= n) return;
  if (nB >= n) nB = n - 1;
  int half = lane >> 5;
  int hl   = lane & 31;
  int e0a = __builtin_amdgcn_readfirstlane(off[nA]);
  int e0b = __builtin_amdgcn_readfirstlane(off[nB]);
  int e1b = __builtin_amdgcn_readfirstlane(off[nB + 1]);
  int degA = e0b - e0a, degB = e1b - e0b;

  const ushort_t* sp = support + hl * 2;
  const int* epA = (const int*)(edata + e0a);
  const int* epB = (const int*)(edata + e0b);

  float axA[4] = {}, ayA[4] = {}, axB[4] = {}, ayB[4] = {};

  // ---- flat gather bodies: int2 meta once, then gathers (A,B back-to-back) ----
  int2 mA[16], mB[16];
#pragma unroll
  for (int j = 0; j < 16; ++j) {
    int rel = 2 * j + half;
    mA[j] = *(const int2*)(epA + (rel < degA ? rel : 0) * 2);
  }
#pragma unroll
  for (int j = 0; j < 16; ++j) {
    int rel = 2 * j + half;
    mB[j] = *(const int2*)(epB + (rel < degB ? rel : 0) * 2);
  }
  unsigned int uA[16], uB[16];
#pragma unroll
  for (int j = 0; j < 16; ++j)
    uA[j] = *(const unsigned int*)(sp + ((size_t)mA[j].x << 6));
#pragma unroll
  for (int j = 0; j < 16; ++j)
    uB[j] = *(const unsigned int*)(sp + ((size_t)mB[j].x << 6));
#pragma unroll
  for (int j = 0; j < 16; ++j) {
    int rel = 2 * j + half;
    float w = (rel < degA) ? __int_as_float(mA[j].y) : 0.0f;
    axA[j & 3] += w * __int_as_float(uA[j] << 16);
    ayA[j & 3] += w * __int_as_float(uA[j] & 0xffff0000u);
  }
#pragma unroll
  for (int j = 0; j < 16; ++j) {
    int rel = 2 * j + half;
    float w = (rel < degB) ? __int_as_float(mB[j].y) : 0.0f;
    axB[j & 3] += w * __int_as_float(uB[j] << 16);
    ayB[j & 3] += w * __int_as_float(uB[j] & 0xffff0000u);
  }
  // ---- rare remainder (deg > 32) ----
  for (int it = 32; it < degA; it += 16) {
    int2 ed[8];
#pragma unroll
    for (int j = 0; j < 8; ++j) {
      int rel = it + 2 * j + half;
      ed[j] = *(const int2*)(epA + (rel < degA ? rel : 0) * 2);
    }
    unsigned int uu[8];
#pragma unroll
    for (int j = 0; j < 8; ++j)
      uu[j] = *(const unsigned int*)(sp + ((size_t)ed[j].x << 6));
#pragma unroll
    for (int j = 0; j < 8; ++j) {
      int rel = it + 2 * j + half;
      float w = (rel < degA) ? __int_as_float(ed[j].y) : 0.0f;
      axA[j & 3] += w * __int_as_float(uu[j] << 16);
      ayA[j & 3] += w * __int_as_float(uu[j] & 0xffff0000u);
    }
  }
  for (int it = 32; it < degB; it += 16) {
    int2 ed[8];
#pragma unroll
    for (int j = 0; j < 8; ++j) {
      int rel = it + 2 * j + half;
      ed[j] = *(const int2*)(epB + (rel < degB ? rel : 0) * 2);
    }
    unsigned int uu[8];
#pragma unroll
    for (int j = 0; j < 8; ++j)
      uu[j] = *(const unsigned int*)(sp + ((size_t)ed[j].x << 6));
#pragma unroll
    for (int j = 0; j < 8; ++j) {
      int rel = it + 2 * j + half;
      float w = (rel < degB) ? __int_as_float(ed[j].y) : 0.0f;
      axB[j & 3] += w * __int_as_float(uu[j] << 16);
      ayB[j & 3] += w * __int_as_float(uu[j] & 0xffff0000u);
    }
  }

  float sxA = ((axA[0] + axA[1]) + (axA[2] + axA[3]));
  float syA = ((ayA[0] + ayA[1]) + (ayA[2] + ayA[3]));
  float sxB = ((axB[0] + axB[1]) + (axB[2] + axB[3]));
  float syB = ((ayB[0] + ayB[1]) + (ayB[2] + ayB[3]));
  sxA += __shfl_xor(sxA, 32, 64);
  syA += __shfl_xor(syA, 32, 64);
  sxB += __shfl_xor(sxB, 32, 64);
  syB += __shfl_xor(syB, 32, 64);

  // ---- h epilogue: bias, relu, residual; h -> LDS (+global if needed) ----
  int node = (half == 0) ? nA : nB;
  float2 bv = *(const float2*)&bias[hl * 2];
  float vx = ((half == 0) ? sxA : sxB) + bv.x;
  float vy = ((half == 0) ? syA : syB) + bv.y;
  vx = fmaxf(vx, 0.0f); vy = fmaxf(vy, 0.0f);
  if (resid) {
    float2 r = *(const float2*)&resid[(size_t)node * 64 + hl * 2];
    vx += r.x; vy += r.y;
  }
  if (WRITE_H)
    *(float2*)&hout[(size_t)node * 64 + hl * 2] = make_float2(vx, vy);
  *(float2*)&hls[wv][half][hl * 2] = make_float2(vx, vy);
  __threadfence_block();   // drain ds_write before same-wave cross-lane reads

  // ---- fused GEMM: lane = (s2 = k-half, q = col-quad) within its half ----
  int s2 = hl >> 4;        // 0: k 0..31, 1: k 32..63
  int q  = hl & 15;        // cols 4q..4q+3
  int k0 = s2 * 32;
  const float* hb = hls[wv][half];
  float o0 = 0.f, o1 = 0.f, o2 = 0.f, o3 = 0.f;
#pragma unroll
  for (int kk = 0; kk < 32; kk += 4) {
    float4 h4 = *(const float4*)&hb[k0 + kk];
    float4 w0 = *(const float4*)&Wl[(k0 + kk + 0) * 64 + q * 4];
    float4 w1 = *(const float4*)&Wl[(k0 + kk + 1) * 64 + q * 4];
    float4 w2 = *(const float4*)&Wl[(k0 + kk + 2) * 64 + q * 4];
    float4 w3 = *(const float4*)&Wl[(k0 + kk + 3) * 64 + q * 4];
    o0 += h4.x * w0.x + h4.y * w1.x + h4.z * w2.x + h4.w * w3.x;
    o1 += h4.x * w0.y + h4.y * w1.y + h4.z * w2.y + h4.w * w3.y;
    o2 += h4.x * w0.z + h4.y * w1.z + h4.z * w2.z + h4.w * w3.z;
    o3 += h4.x * w0.w + h4.y * w1.w + h4.z * w2.w + h4.w * w3.w;
  }
  o0 += __shfl_xor(o0, 16, 64);
  o1 += __shfl_xor(o1, 16, 64);
  o2 += __shfl_xor(o2, 16, 64);
  o3 += __shfl_xor(o3, 16, 64);
  if (s2 == 0 && (FO == 64 || q * 4 < FO)) {
    unsigned int p0 = (unsigned int)f2bf(o0) | ((unsigned int)f2bf(o1) << 16);
    unsigned int p1 = (unsigned int)f2bf(o2) | ((unsigned int)f2bf(o3) << 16);
    *(uint2*)&sout[(size_t)node * FO + q * 4] = make_uint2(p0, p1);
  }
}

// Final layer: FO=40 aggregation + bias + log_softmax, two nodes per wave.
// Same int2-meta flat gather bodies.
__global__ __launch_bounds__(256, 4) void agg_final_k(
    const ushort_t* __restrict__ support,
    const int2* __restrict__ edata,
    const int* __restrict__ off,
    const float* __restrict__ bias,
    float* __restrict__ out, int n) {
  int tid = blockIdx.x * blockDim.x + threadIdx.x;
  int p = tid >> 6, lane = tid & 63;
  int nA = 2 * p, nB = 2 * p + 1;
  if (nA >= n) return;
  if (nB >= n) nB = n - 1;
  int half = lane >> 5;
  int hl   = lane & 31;
  int col  = (hl < 20 ? hl : 0) * 2;
  int e0a = __builtin_amdgcn_readfirstlane(off[nA]);
  int e0b = __builtin_amdgcn_readfirstlane(off[nB]);
  int e1b = __builtin_amdgcn_readfirstlane(off[nB + 1]);
  int degA = e0b - e0a, degB = e1b - e0b;

  const ushort_t* sp = support + col;
  const int* epA = (const int*)(edata + e0a);
  const int* epB = (const int*)(edata + e0b);

  float axA[4] = {}, ayA[4] = {}, axB[4] = {}, ayB[4] = {};

  int2 mA[16], mB[16];
#pragma unroll
  for (int j = 0; j < 16; ++j) {
    int rel = 2 * j + half;
    mA[j] = *(const int2*)(epA + (rel < degA ? rel : 0) * 2);
  }
#pragma unroll
  for (int j = 0; j < 16; ++j) {
    int rel = 2 * j + half;
    mB[j] = *(const int2*)(epB + (rel < degB ? rel : 0) * 2);
  }
  unsigned int uA[16], uB[16];
#pragma unroll
  for (int j = 0; j < 16; ++j)
    uA[j] = *(const unsigned int*)(sp + (size_t)mA[j].x * NCLASS);
#pragma unroll
  for (int j = 0; j < 16; ++j)
    uB[j] = *(const unsigned int*)(sp + (size_t)mB[j].x * NCLASS);
#pragma unroll
  for (int j = 0; j < 16; ++j) {
    int rel = 2 * j + half;
    float w = (rel < degA) ? __int_as_float(mA[j].y) : 0.0f;
    axA[j & 3] += w * __int_as_float(uA[j] << 16);
    ayA[j & 3] += w * __int_as_float(uA[j] & 0xffff0000u);
  }
#pragma unroll
  for (int j = 0; j < 16; ++j) {
    int rel = 2 * j + half;
    float w = (rel < degB) ? __int_as_float(mB[j].y) : 0.0f;
    axB[j & 3] += w * __int_as_float(uB[j] << 16);
    ayB[j & 3] += w * __int_as_float(uB[j] & 0xffff0000u);
  }
  for (int it = 32; it < degA; it += 16) {
    int2 ed[8];
#pragma unroll
    for (int j = 0; j < 8; ++j) {
      int rel = it + 2 * j + half;
      ed[j] = *(const int2*)(epA + (rel < degA ? rel : 0) * 2);
    }
    unsigned int uu[8];
#pragma unroll
    for (int j = 0; j < 8; ++j)
      uu[j] = *(const unsigned int*)(sp + (size_t)ed[j].x * NCLASS);
#pragma unroll
    for (int j = 0; j < 8; ++j) {
      int rel = it + 2 * j + half;
      float w = (rel < degA) ? __int_as_float(ed[j].y) : 0.0f;
      axA[j & 3] += w * __int_as_float(uu[j] << 16);
      ayA[j & 3] += w * __int_as_float(uu[j] & 0xffff0000u);
    }
  }
  for (int it = 32; it < degB; it += 16) {
    int2 ed[8];
#pragma unroll
    for (int j = 0; j < 8; ++j) {
      int rel = it + 2 * j + half;
      ed[j] = *(const int2*)(epB + (rel < degB ? rel : 0) * 2);
    }
    unsigned int uu[8];
#pragma unroll
    for (int j = 0; j < 8; ++j)
      uu[j] = *(const unsigned int*)(sp + (size_t)ed[j].x * NCLASS);
#pragma unroll
    for (int j = 0; j < 8; ++j) {
      int rel = it + 2 * j + half;
      float w = (rel < degB) ? __int_as_float(ed[j].y) : 0.0f;
      axB[j & 3] += w * __int_as_float(uu[j] << 16);
      ayB[j & 3] += w * __int_as_float(uu[j] & 0xffff0000u);
    }
  }

  float sxA = ((axA[0] + axA[1]) + (axA[2] + axA[3]));
  float syA = ((ayA[0] + ayA[1]) + (ayA[2] + ayA[3]));
  float sxB = ((axB[0] + axB[1]) + (axB[2] + axB[3]));
  float syB = ((ayB[0] + ayB[1]) + (ayB[2] + ayB[3]));
  sxA += __shfl_xor(sxA, 32, 64);
  syA += __shfl_xor(syA, 32, 64);
  sxB += __shfl_xor(sxB, 32, 64);
  syB += __shfl_xor(syB, 32, 64);

  bool valid = (hl < 20);
  float2 bv = *(const float2*)&bias[col];
  float vxA = sxA + bv.x, vyA = syA + bv.y;
  float vxB = sxB + bv.x, vyB = syB + bv.y;

  float mA2 = valid ? fmaxf(vxA, vyA) : -INFINITY;
  float mB2 = valid ? fmaxf(vxB, vyB) : -INFINITY;
#pragma unroll
  for (int d = 32; d; d >>= 1) {
    mA2 = fmaxf(mA2, __shfl_xor(mA2, d, 64));
    mB2 = fmaxf(mB2, __shfl_xor(mB2, d, 64));
  }
  float exA = (valid && half == 0) ? (expf(vxA - mA2) + expf(vyA - mA2)) : 0.0f;
  float exB = (valid && half == 0) ? (expf(vxB - mB2) + expf(vyB - mB2)) : 0.0f;
  float sA2 = exA, sB2 = exB;
#pragma unroll
  for (int d = 32; d; d >>= 1) {
    sA2 += __shfl_xor(sA2, d, 64);
    sB2 += __shfl_xor(sB2, d, 64);
  }
  if (valid) {
    if (half == 0) {
      float ls = logf(sA2);
      *(float2*)&out[(size_t)nA * NCLASS + hl * 2] =
          make_float2(vxA - mA2 - ls, vyA - mA2 - ls);
    } else {
      float ls = logf(sB2);
      *(float2*)&out[(size_t)nB * NCLASS + hl * 2] =
          make_float2(vxB - mB2 - ls, vyB - mB2 - ls);
    }
  }
}

extern "C" void kernel_launch(void* const* d_in, const int* in_sizes, int n_in,
                              void* d_out, int out_size, void* d_ws, size_t ws_size,
                              hipStream_t stream) {
  const float* x   = (const float*)d_in[0];
  const int*   src = (const int*)d_in[1];
  const int*   dst = (const int*)d_in[2];
  const float* ew  = (const float*)d_in[3];
  const float* W[7]; const float* b[7];
  for (int i = 0; i < 7; ++i) {
    W[i] = (const float*)d_in[4 + 2 * i];
    b[i] = (const float*)d_in[5 + 2 * i];
  }
  int N = in_sizes[0] / NFEAT;   // 65536
  int E = in_sizes[1];           // 1048576

  char* ws = (char*)d_ws;
  int*      off     = (int*)(ws + 0);                 // (N+1) ints
  int*      bsum    = (int*)(ws + (1ll << 20));       // 256 ints
  int*      cnt4    = (int*)(ws + (2ll << 20));       // 4N ints = 1MB
  int4*     sb4     = (int4*)(ws + (3ll << 20));      // N int4 = 1MB
  int2*     edata   = (int2*)(ws + (4ll << 20));      // E int2 = 8MB
  int*      rank    = (int*)(ws + (12ll << 20));      // E ints = 4MB
  ushort_t* SA      = (ushort_t*)(ws + (16ll << 20)); // N*64 bf16 = 8MB
  ushort_t* SB      = (ushort_t*)(ws + (24ll << 20)); // N*64 bf16 = 8MB
  float*    hA      = (float*)(ws + (32ll << 20));    // 16MB
  float*    hB      = (float*)(ws + (48ll << 20));    // 16MB

  // ---- CSR build (rank co-scheduled with L1 GEMM) ----
  (void)hipMemsetAsync(cnt4, 0, (size_t)4 * N * sizeof(int), stream);
  rankgemm_k<<<2048, 256, 0, stream>>>(x, W[0], SA, dst, cnt4, rank, E, N);
  int nb = (N + 255) / 256;
  scan1_k<<<nb, 256, 0, stream>>>(cnt4, off, bsum, sb4, N);
  scan2_k<<<1, 256, 0, stream>>>(bsum, nb);
  scan3_k<<<nb, 256, 0, stream>>>(off, bsum, N, E);
  fill_k<<<(E / 4 + 255) / 256, 256, 0, stream>>>(src, dst, ew, off, rank,
                                                  (const int*)sb4, edata, E);

  int gb_agg = N / 8;   // 2 nodes/wave, 4 waves/block

  // K2: h1 = relu(agg(S1)+b1); S2 = h1@W2
  aggemm_k<64, false><<<gb_agg, 256, 0, stream>>>(SA, edata, off, b[0], nullptr,
                                                  W[1], SB, nullptr, N);
  // K3: h2 = relu(agg(S2)+b2); S3 = h2@W3; keep h2
  aggemm_k<64, true><<<gb_agg, 256, 0, stream>>>(SB, edata, off, b[1], nullptr,
                                                 W[2], SA, hA, N);
  // K4: h3 = relu(agg(S3)+b3)+h2; S4 = h3@W4; keep h3
  aggemm_k<64, true><<<gb_agg, 256, 0, stream>>>(SA, edata, off, b[2], hA,
                                                 W[3], SB, hB, N);
  // K5: h4 = relu(agg(S4)+b4)+h3; S5 = h4@W5; keep h4
  aggemm_k<64, true><<<gb_agg, 256, 0, stream>>>(SB, edata, off, b[3], hB,
                                                 W[4], SA, hA, N);
  // K6: h5 = relu(agg(S5)+b5)+h4; S6 = h5@W6
  aggemm_k<64, false><<<gb_agg, 256, 0, stream>>>(SA, edata, off, b[4], hA,
                                                  W[5], SB, nullptr, N);
  // K7: h6 = relu(agg(S6)+b6); S7 = h6@W7 (64->40)
  aggemm_k<40, false><<<gb_agg, 256, 0, stream>>>(SB, edata, off, b[5], nullptr,
                                                  W[6], SA, nullptr, N);
  // K8: out = log_softmax(agg(S7)+b7)
  agg_final_k<<<gb_agg, 256, 0, stream>>>(SA, edata, off, b[6], (float*)d_out, N);
}

// Round 16
// 477.909 us; speedup vs baseline: 1.0390x; 1.0390x over previous
//
#include <hip/hip_runtime.h>
#include <math.h>

// GCN: 7 graph-conv layers. N=65536 nodes, E=1048576 edges, feat 128->64(x6)->40.
// dst-CSR once per call (rank co-scheduled with L1 GEMM); 6x fused{pull-
// aggregate (2 nodes/wave, int2 edge meta) + LDS-W float2 GEMM}; final agg.

constexpr int NFEAT = 128, NHID = 64, NCLASS = 40;

typedef unsigned short ushort_t;
typedef int ivec4 __attribute__((ext_vector_type(4)));

__device__ inline ushort_t f2bf(float f) {  // round-to-nearest-even
  union { float f; unsigned int i; } v; v.f = f;
  unsigned int lsb = (v.i >> 16) & 1u;
  v.i += 0x7fffu + lsb;
  return (ushort_t)(v.i >> 16);
}

// Merged: even blocks run the L1 GEMM (S1 = x@W1, 64x64 tile); odd blocks run
// the rank histogram. gemm VALU work fills rank's atomic-latency bubbles.
__global__ __launch_bounds__(256) void rankgemm_k(
    const float* __restrict__ x, const float* __restrict__ W1,
    ushort_t* __restrict__ sout,
    const int* __restrict__ dst, int* __restrict__ cnt4,
    int* __restrict__ rank, int E, int N) {
  constexpr int HS = 68;
  __shared__ float hl[64 * HS];
  __shared__ float wl[64 * 64];
  int tid = threadIdx.x;
  int bid = blockIdx.x;

  if (bid & 1) {
    int i = (bid >> 1) * 256 + tid;
    int base = i * 4;
    if (base >= E) return;
    int4 d4 = *(const int4*)(dst + base);
    int r0 = atomicAdd(&cnt4[0 * N + d4.x], 1);
    int r1 = atomicAdd(&cnt4[1 * N + d4.y], 1);
    int r2 = atomicAdd(&cnt4[2 * N + d4.z], 1);
    int r3 = atomicAdd(&cnt4[3 * N + d4.w], 1);
    ivec4 rr = { (r0 << 2) | 0, (r1 << 2) | 1, (r2 << 2) | 2, (r3 << 2) | 3 };
    __builtin_nontemporal_store(rr, (ivec4*)(rank + base));
    return;
  }

  int row0 = (bid >> 1) * 64;
  int tx = tid & 15, ty = tid >> 4;
  float acc[4][4] = {};
  for (int kc = 0; kc < 128; kc += 64) {
    {
      const float* hb = x + (size_t)row0 * 128 + kc;
      for (int i = tid; i < 64 * 16; i += 256) {
        int r = i >> 4, kk = (i & 15) << 2;
        float4 v = *(const float4*)(hb + (size_t)r * 128 + kk);
        *(float4*)&hl[r * HS + kk] = v;
      }
    }
    {
      const float4* Wb = (const float4*)(W1 + (size_t)kc * 64);
      for (int i = tid; i < 64 * 16; i += 256) ((float4*)wl)[i] = Wb[i];
    }
    __syncthreads();
    for (int k4 = 0; k4 < 64; k4 += 4) {
      float4 a[4];
#pragma unroll
      for (int r = 0; r < 4; ++r)
        a[r] = *(const float4*)&hl[(ty * 4 + r) * HS + k4];
#pragma unroll
      for (int j = 0; j < 4; ++j) {
        float4 bv = *(const float4*)&wl[(k4 + j) * 64 + tx * 4];
        const float* bp = (const float*)&bv;
#pragma unroll
        for (int r = 0; r < 4; ++r) {
          const float* ap = (const float*)&a[r];
#pragma unroll
          for (int c = 0; c < 4; ++c) acc[r][c] += ap[j] * bp[c];
        }
      }
    }
    __syncthreads();
  }
#pragma unroll
  for (int r = 0; r < 4; ++r) {
    ushort_t pk[4];
#pragma unroll
    for (int c = 0; c < 4; ++c) pk[c] = f2bf(acc[r][c]);
    *(ushort4*)&sout[(size_t)(row0 + ty * 4 + r) * 64 + tx * 4] =
        make_ushort4(pk[0], pk[1], pk[2], pk[3]);
  }
}

__global__ void scan1_k(const int* __restrict__ cnt4, int* __restrict__ off,
                        int* __restrict__ bsum, int4* __restrict__ sb4, int n) {
  __shared__ int tmp[256];
  int tid = threadIdx.x;
  int i = blockIdx.x * 256 + tid;
  int c0 = 0, c1 = 0, c2 = 0, c3 = 0;
  if (i < n) {
    c0 = cnt4[i]; c1 = cnt4[n + i]; c2 = cnt4[2 * n + i]; c3 = cnt4[3 * n + i];
  }
  int v = c0 + c1 + c2 + c3;
  tmp[tid] = v;
  __syncthreads();
  for (int d = 1; d < 256; d <<= 1) {
    int t = (tid >= d) ? tmp[tid - d] : 0;
    __syncthreads();
    tmp[tid] += t;
    __syncthreads();
  }
  if (i < n) {
    off[i] = tmp[tid] - v;
    sb4[i] = make_int4(0, c0, c0 + c1, c0 + c1 + c2);
  }
  if (tid == 255) bsum[blockIdx.x] = tmp[255];
}

__global__ void scan2_k(int* __restrict__ bsum, int nb) {
  __shared__ int tmp[256];
  int tid = threadIdx.x;
  int v = (tid < nb) ? bsum[tid] : 0;
  tmp[tid] = v;
  __syncthreads();
  for (int d = 1; d < 256; d <<= 1) {
    int t = (tid >= d) ? tmp[tid - d] : 0;
    __syncthreads();
    tmp[tid] += t;
    __syncthreads();
  }
  if (tid < nb) bsum[tid] = tmp[tid] - v;
}

__global__ void scan3_k(int* __restrict__ off, const int* __restrict__ bsum, int n, int E) {
  int i = blockIdx.x * blockDim.x + threadIdx.x;
  if (i < n) off[i] += bsum[i >> 8];
  if (i == 0) off[n] = E;
}

__global__ void fill_k(const int* __restrict__ src, const int* __restrict__ dst,
                       const float* __restrict__ w, const int* __restrict__ off,
                       const int* __restrict__ rank, const int* __restrict__ sb4,
                       int2* __restrict__ edata, int E) {
  int i = blockIdx.x * blockDim.x + threadIdx.x;
  int base = i * 4;
  if (base >= E) return;
  int4 s4 = *(const int4*)(src + base);
  int4 d4 = *(const int4*)(dst + base);
  float4 w4 = *(const float4*)(w + base);
  int4 r4 = *(const int4*)(rank + base);
  int dd[4] = { d4.x, d4.y, d4.z, d4.w };
  int rr[4] = { r4.x, r4.y, r4.z, r4.w };
  int ss[4] = { s4.x, s4.y, s4.z, s4.w };
  float ww[4] = { w4.x, w4.y, w4.z, w4.w };
  int ob[4], sb[4];
#pragma unroll
  for (int k = 0; k < 4; ++k) ob[k] = off[dd[k]];
#pragma unroll
  for (int k = 0; k < 4; ++k) sb[k] = sb4[dd[k] * 4 + (rr[k] & 3)];
#pragma unroll
  for (int k = 0; k < 4; ++k) {
    int pos = ob[k] + sb[k] + (rr[k] >> 2);
    int2 v = make_int2(ss[k], __float_as_int(ww[k]));
    __builtin_nontemporal_store(*(const long long*)&v, (long long*)&edata[pos]);
  }
}

// Fused pull-aggregate + next-layer GEMM (R14-proven structure; single change:
// flat bodies load int2 edge meta once per slot instead of separate src/w).
// Two nodes per wave (A: lanes 0-31, B: lanes 32-63 for edge parity; each
// lane owns feature pair 2hl,2hl+1), flat-issue 2x16 gathers in flight.
// GEMM: W staged in LDS; float2 column reads at col2=2*hl (2-way alias, free).
template<int FO, bool WRITE_H>
__global__ __launch_bounds__(256, 4) void aggemm_k(
    const ushort_t* __restrict__ support,   // N x 64 bf16 (layer input S)
    const int2* __restrict__ edata,
    const int* __restrict__ off,
    const float* __restrict__ bias,         // 64
    const float* __restrict__ resid,        // N x 64 f32 or null
    const float* __restrict__ Wn,           // 64 x FO
    ushort_t* __restrict__ sout,            // N x FO bf16 (next layer S)
    float* __restrict__ hout,               // N x 64 f32 (if WRITE_H)
    int n) {
  __shared__ float Wl[64 * FO];
  __shared__ float hls[4][2][64];
  int tid = threadIdx.x;
  for (int i = tid; i < (64 * FO) / 4; i += 256)
    ((float4*)Wl)[i] = ((const float4*)Wn)[i];
  __syncthreads();

  int p = (blockIdx.x * blockDim.x + tid) >> 6, lane = tid & 63;
  int wv = tid >> 6;
  int nA = 2 * p, nB = 2 * p + 1;
  if (nA >= n) return;
  if (nB >= n) nB = n - 1;
  int half = lane >> 5;
  int hl   = lane & 31;
  int e0a = __builtin_amdgcn_readfirstlane(off[nA]);
  int e0b = __builtin_amdgcn_readfirstlane(off[nB]);
  int e1b = __builtin_amdgcn_readfirstlane(off[nB + 1]);
  int degA = e0b - e0a, degB = e1b - e0b;

  const ushort_t* sp = support + hl * 2;
  const int* epA = (const int*)(edata + e0a);
  const int* epB = (const int*)(edata + e0b);

  float axA[4] = {}, ayA[4] = {}, axB[4] = {}, ayB[4] = {};

  // ---- flat gather bodies: int2 meta once, then gathers (A,B back-to-back) ----
  int2 mA[16], mB[16];
#pragma unroll
  for (int j = 0; j < 16; ++j) {
    int rel = 2 * j + half;
    mA[j] = *(const int2*)(epA + (rel < degA ? rel : 0) * 2);
  }
#pragma unroll
  for (int j = 0; j < 16; ++j) {
    int rel = 2 * j + half;
    mB[j] = *(const int2*)(epB + (rel < degB ? rel : 0) * 2);
  }
  unsigned int uA[16], uB[16];
#pragma unroll
  for (int j = 0; j < 16; ++j)
    uA[j] = *(const unsigned int*)(sp + ((size_t)mA[j].x << 6));
#pragma unroll
  for (int j = 0; j < 16; ++j)
    uB[j] = *(const unsigned int*)(sp + ((size_t)mB[j].x << 6));
#pragma unroll
  for (int j = 0; j < 16; ++j) {
    int rel = 2 * j + half;
    float w = (rel < degA) ? __int_as_float(mA[j].y) : 0.0f;
    axA[j & 3] += w * __int_as_float(uA[j] << 16);
    ayA[j & 3] += w * __int_as_float(uA[j] & 0xffff0000u);
  }
#pragma unroll
  for (int j = 0; j < 16; ++j) {
    int rel = 2 * j + half;
    float w = (rel < degB) ? __int_as_float(mB[j].y) : 0.0f;
    axB[j & 3] += w * __int_as_float(uB[j] << 16);
    ayB[j & 3] += w * __int_as_float(uB[j] & 0xffff0000u);
  }
  // ---- rare remainder (deg > 32) ----
  for (int it = 32; it < degA; it += 16) {
    int2 ed[8];
#pragma unroll
    for (int j = 0; j < 8; ++j) {
      int rel = it + 2 * j + half;
      ed[j] = *(const int2*)(epA + (rel < degA ? rel : 0) * 2);
    }
    unsigned int uu[8];
#pragma unroll
    for (int j = 0; j < 8; ++j)
      uu[j] = *(const unsigned int*)(sp + ((size_t)ed[j].x << 6));
#pragma unroll
    for (int j = 0; j < 8; ++j) {
      int rel = it + 2 * j + half;
      float w = (rel < degA) ? __int_as_float(ed[j].y) : 0.0f;
      axA[j & 3] += w * __int_as_float(uu[j] << 16);
      ayA[j & 3] += w * __int_as_float(uu[j] & 0xffff0000u);
    }
  }
  for (int it = 32; it < degB; it += 16) {
    int2 ed[8];
#pragma unroll
    for (int j = 0; j < 8; ++j) {
      int rel = it + 2 * j + half;
      ed[j] = *(const int2*)(epB + (rel < degB ? rel : 0) * 2);
    }
    unsigned int uu[8];
#pragma unroll
    for (int j = 0; j < 8; ++j)
      uu[j] = *(const unsigned int*)(sp + ((size_t)ed[j].x << 6));
#pragma unroll
    for (int j = 0; j < 8; ++j) {
      int rel = it + 2 * j + half;
      float w = (rel < degB) ? __int_as_float(ed[j].y) : 0.0f;
      axB[j & 3] += w * __int_as_float(uu[j] << 16);
      ayB[j & 3] += w * __int_as_float(uu[j] & 0xffff0000u);
    }
  }

  float sxA = ((axA[0] + axA[1]) + (axA[2] + axA[3]));
  float syA = ((ayA[0] + ayA[1]) + (ayA[2] + ayA[3]));
  float sxB = ((axB[0] + axB[1]) + (axB[2] + axB[3]));
  float syB = ((ayB[0] + ayB[1]) + (ayB[2] + ayB[3]));
  sxA += __shfl_xor(sxA, 32, 64);
  syA += __shfl_xor(syA, 32, 64);
  sxB += __shfl_xor(sxB, 32, 64);
  syB += __shfl_xor(syB, 32, 64);

  // ---- h epilogue: bias, relu, residual; h -> LDS (+global if needed) ----
  int node = (half == 0) ? nA : nB;
  float2 bv = *(const float2*)&bias[hl * 2];
  float vx = ((half == 0) ? sxA : sxB) + bv.x;
  float vy = ((half == 0) ? syA : syB) + bv.y;
  vx = fmaxf(vx, 0.0f); vy = fmaxf(vy, 0.0f);
  if (resid) {
    float2 r = *(const float2*)&resid[(size_t)node * 64 + hl * 2];
    vx += r.x; vy += r.y;
  }
  if (WRITE_H)
    *(float2*)&hout[(size_t)node * 64 + hl * 2] = make_float2(vx, vy);
  *(float2*)&hls[wv][half][hl * 2] = make_float2(vx, vy);
  __threadfence_block();   // drain ds_write before same-wave cross-lane reads

  // ---- fused GEMM: S_next[node][2hl,2hl+1] = h[node] @ Wn ----
  int col2 = (2 * hl < FO) ? 2 * hl : 0;
  const float* hb = hls[wv][half];
  float ox0 = 0.f, ox1 = 0.f, oy0 = 0.f, oy1 = 0.f;
#pragma unroll
  for (int k = 0; k < 64; k += 4) {
    float4 hv = *(const float4*)&hb[k];   // broadcast within half
    float2 w0 = *(const float2*)&Wl[(k + 0) * FO + col2];
    float2 w1 = *(const float2*)&Wl[(k + 1) * FO + col2];
    float2 w2 = *(const float2*)&Wl[(k + 2) * FO + col2];
    float2 w3 = *(const float2*)&Wl[(k + 3) * FO + col2];
    ox0 += hv.x * w0.x; oy0 += hv.x * w0.y;
    ox1 += hv.y * w1.x; oy1 += hv.y * w1.y;
    ox0 += hv.z * w2.x; oy0 += hv.z * w2.y;
    ox1 += hv.w * w3.x; oy1 += hv.w * w3.y;
  }
  float ox = ox0 + ox1, oy = oy0 + oy1;
  unsigned int pk = (unsigned int)f2bf(ox) | ((unsigned int)f2bf(oy) << 16);
  if (2 * hl < FO)
    *(unsigned int*)&sout[(size_t)node * FO + 2 * hl] = pk;
}

// Final layer: FO=40 aggregation + bias + log_softmax, two nodes per wave.
// Same int2-meta flat gather bodies.
__global__ __launch_bounds__(256, 4) void agg_final_k(
    const ushort_t* __restrict__ support,
    const int2* __restrict__ edata,
    const int* __restrict__ off,
    const float* __restrict__ bias,
    float* __restrict__ out, int n) {
  int tid = blockIdx.x * blockDim.x + threadIdx.x;
  int p = tid >> 6, lane = tid & 63;
  int nA = 2 * p, nB = 2 * p + 1;
  if (nA >= n) return;
  if (nB >= n) nB = n - 1;
  int half = lane >> 5;
  int hl   = lane & 31;
  int col  = (hl < 20 ? hl : 0) * 2;
  int e0a = __builtin_amdgcn_readfirstlane(off[nA]);
  int e0b = __builtin_amdgcn_readfirstlane(off[nB]);
  int e1b = __builtin_amdgcn_readfirstlane(off[nB + 1]);
  int degA = e0b - e0a, degB = e1b - e0b;

  const ushort_t* sp = support + col;
  const int* epA = (const int*)(edata + e0a);
  const int* epB = (const int*)(edata + e0b);

  float axA[4] = {}, ayA[4] = {}, axB[4] = {}, ayB[4] = {};

  int2 mA[16], mB[16];
#pragma unroll
  for (int j = 0; j < 16; ++j) {
    int rel = 2 * j + half;
    mA[j] = *(const int2*)(epA + (rel < degA ? rel : 0) * 2);
  }
#pragma unroll
  for (int j = 0; j < 16; ++j) {
    int rel = 2 * j + half;
    mB[j] = *(const int2*)(epB + (rel < degB ? rel : 0) * 2);
  }
  unsigned int uA[16], uB[16];
#pragma unroll
  for (int j = 0; j < 16; ++j)
    uA[j] = *(const unsigned int*)(sp + (size_t)mA[j].x * NCLASS);
#pragma unroll
  for (int j = 0; j < 16; ++j)
    uB[j] = *(const unsigned int*)(sp + (size_t)mB[j].x * NCLASS);
#pragma unroll
  for (int j = 0; j < 16; ++j) {
    int rel = 2 * j + half;
    float w = (rel < degA) ? __int_as_float(mA[j].y) : 0.0f;
    axA[j & 3] += w * __int_as_float(uA[j] << 16);
    ayA[j & 3] += w * __int_as_float(uA[j] & 0xffff0000u);
  }
#pragma unroll
  for (int j = 0; j < 16; ++j) {
    int rel = 2 * j + half;
    float w = (rel < degB) ? __int_as_float(mB[j].y) : 0.0f;
    axB[j & 3] += w * __int_as_float(uB[j] << 16);
    ayB[j & 3] += w * __int_as_float(uB[j] & 0xffff0000u);
  }
  for (int it = 32; it < degA; it += 16) {
    int2 ed[8];
#pragma unroll
    for (int j = 0; j < 8; ++j) {
      int rel = it + 2 * j + half;
      ed[j] = *(const int2*)(epA + (rel < degA ? rel : 0) * 2);
    }
    unsigned int uu[8];
#pragma unroll
    for (int j = 0; j < 8; ++j)
      uu[j] = *(const unsigned int*)(sp + (size_t)ed[j].x * NCLASS);
#pragma unroll
    for (int j = 0; j < 8; ++j) {
      int rel = it + 2 * j + half;
      float w = (rel < degA) ? __int_as_float(ed[j].y) : 0.0f;
      axA[j & 3] += w * __int_as_float(uu[j] << 16);
      ayA[j & 3] += w * __int_as_float(uu[j] & 0xffff0000u);
    }
  }
  for (int it = 32; it < degB; it += 16) {
    int2 ed[8];
#pragma unroll
    for (int j = 0; j < 8; ++j) {
      int rel = it + 2 * j + half;
      ed[j] = *(const int2*)(epB + (rel < degB ? rel : 0) * 2);
    }
    unsigned int uu[8];
#pragma unroll
    for (int j = 0; j < 8; ++j)
      uu[j] = *(const unsigned int*)(sp + (size_t)ed[j].x * NCLASS);
#pragma unroll
    for (int j = 0; j < 8; ++j) {
      int rel = it + 2 * j + half;
      float w = (rel < degB) ? __int_as_float(ed[j].y) : 0.0f;
      axB[j & 3] += w * __int_as_float(uu[j] << 16);
      ayB[j & 3] += w * __int_as_float(uu[j] & 0xffff0000u);
    }
  }

  float sxA = ((axA[0] + axA[1]) + (axA[2] + axA[3]));
  float syA = ((ayA[0] + ayA[1]) + (ayA[2] + ayA[3]));
  float sxB = ((axB[0] + axB[1]) + (axB[2] + axB[3]));
  float syB = ((ayB[0] + ayB[1]) + (ayB[2] + ayB[3]));
  sxA += __shfl_xor(sxA, 32, 64);
  syA += __shfl_xor(syA, 32, 64);
  sxB += __shfl_xor(sxB, 32, 64);
  syB += __shfl_xor(syB, 32, 64);

  bool valid = (hl < 20);
  float2 bv = *(const float2*)&bias[col];
  float vxA = sxA + bv.x, vyA = syA + bv.y;
  float vxB = sxB + bv.x, vyB = syB + bv.y;

  float mA2 = valid ? fmaxf(vxA, vyA) : -INFINITY;
  float mB2 = valid ? fmaxf(vxB, vyB) : -INFINITY;
#pragma unroll
  for (int d = 32; d; d >>= 1) {
    mA2 = fmaxf(mA2, __shfl_xor(mA2, d, 64));
    mB2 = fmaxf(mB2, __shfl_xor(mB2, d, 64));
  }
  float exA = (valid && half == 0) ? (expf(vxA - mA2) + expf(vyA - mA2)) : 0.0f;
  float exB = (valid && half == 0) ? (expf(vxB - mB2) + expf(vyB - mB2)) : 0.0f;
  float sA2 = exA, sB2 = exB;
#pragma unroll
  for (int d = 32; d; d >>= 1) {
    sA2 += __shfl_xor(sA2, d, 64);
    sB2 += __shfl_xor(sB2, d, 64);
  }
  if (valid) {
    if (half == 0) {
      float ls = logf(sA2);
      *(float2*)&out[(size_t)nA * NCLASS + hl * 2] =
          make_float2(vxA - mA2 - ls, vyA - mA2 - ls);
    } else {
      float ls = logf(sB2);
      *(float2*)&out[(size_t)nB * NCLASS + hl * 2] =
          make_float2(vxB - mB2 - ls, vyB - mB2 - ls);
    }
  }
}

extern "C" void kernel_launch(void* const* d_in, const int* in_sizes, int n_in,
                              void* d_out, int out_size, void* d_ws, size_t ws_size,
                              hipStream_t stream) {
  const float* x   = (const float*)d_in[0];
  const int*   src = (const int*)d_in[1];
  const int*   dst = (const int*)d_in[2];
  const float* ew  = (const float*)d_in[3];
  const float* W[7]; const float* b[7];
  for (int i = 0; i < 7; ++i) {
    W[i] = (const float*)d_in[4 + 2 * i];
    b[i] = (const float*)d_in[5 + 2 * i];
  }
  int N = in_sizes[0] / NFEAT;   // 65536
  int E = in_sizes[1];           // 1048576

  char* ws = (char*)d_ws;
  int*      off     = (int*)(ws + 0);                 // (N+1) ints
  int*      bsum    = (int*)(ws + (1ll << 20));       // 256 ints
  int*      cnt4    = (int*)(ws + (2ll << 20));       // 4N ints = 1MB
  int4*     sb4     = (int4*)(ws + (3ll << 20));      // N int4 = 1MB
  int2*     edata   = (int2*)(ws + (4ll << 20));      // E int2 = 8MB
  int*      rank    = (int*)(ws + (12ll << 20));      // E ints = 4MB
  ushort_t* SA      = (ushort_t*)(ws + (16ll << 20)); // N*64 bf16 = 8MB
  ushort_t* SB      = (ushort_t*)(ws + (24ll << 20)); // N*64 bf16 = 8MB
  float*    hA      = (float*)(ws + (32ll << 20));    // 16MB
  float*    hB      = (float*)(ws + (48ll << 20));    // 16MB

  // ---- CSR build (rank co-scheduled with L1 GEMM) ----
  (void)hipMemsetAsync(cnt4, 0, (size_t)4 * N * sizeof(int), stream);
  rankgemm_k<<<2048, 256, 0, stream>>>(x, W[0], SA, dst, cnt4, rank, E, N);
  int nb = (N + 255) / 256;
  scan1_k<<<nb, 256, 0, stream>>>(cnt4, off, bsum, sb4, N);
  scan2_k<<<1, 256, 0, stream>>>(bsum, nb);
  scan3_k<<<nb, 256, 0, stream>>>(off, bsum, N, E);
  fill_k<<<(E / 4 + 255) / 256, 256, 0, stream>>>(src, dst, ew, off, rank,
                                                  (const int*)sb4, edata, E);

  int gb_agg = N / 8;   // 2 nodes/wave, 4 waves/block

  // K2: h1 = relu(agg(S1)+b1); S2 = h1@W2
  aggemm_k<64, false><<<gb_agg, 256, 0, stream>>>(SA, edata, off, b[0], nullptr,
                                                  W[1], SB, nullptr, N);
  // K3: h2 = relu(agg(S2)+b2); S3 = h2@W3; keep h2
  aggemm_k<64, true><<<gb_agg, 256, 0, stream>>>(SB, edata, off, b[1], nullptr,
                                                 W[2], SA, hA, N);
  // K4: h3 = relu(agg(S3)+b3)+h2; S4 = h3@W4; keep h3
  aggemm_k<64, true><<<gb_agg, 256, 0, stream>>>(SA, edata, off, b[2], hA,
                                                 W[3], SB, hB, N);
  // K5: h4 = relu(agg(S4)+b4)+h3; S5 = h4@W5; keep h4
  aggemm_k<64, true><<<gb_agg, 256, 0, stream>>>(SB, edata, off, b[3], hB,
                                                 W[4], SA, hA, N);
  // K6: h5 = relu(agg(S5)+b5)+h4; S6 = h5@W6
  aggemm_k<64, false><<<gb_agg, 256, 0, stream>>>(SA, edata, off, b[4], hA,
                                                  W[5], SB, nullptr, N);
  // K7: h6 = relu(agg(S6)+b6); S7 = h6@W7 (64->40)
  aggemm_k<40, false><<<gb_agg, 256, 0, stream>>>(SB, edata, off, b[5], nullptr,
                                                  W[6], SA, nullptr, N);
  // K8: out = log_softmax(agg(S7)+b7)
  agg_final_k<<<gb_agg, 256, 0, stream>>>(SA, edata, off, b[6], (float*)d_out, N);
}

// Round 17
// 369.870 us; speedup vs baseline: 1.3425x; 1.2921x over previous
//
#include <hip/hip_runtime.h>
#include <math.h>

// GCN: 7 graph-conv layers. N=65536 nodes, E=1048576 edges, feat 128->64(x6)->40.
// dst-CSR once per call (rank co-scheduled with L1 GEMM); 6x fused{pull-
// aggregate (2 nodes/wave, 32 gathers in flight) + LDS-W GEMM}; final agg.
// R17 == R14 verbatim (proven best, 370 us). R15/R16 aggemm variants regressed.

constexpr int NFEAT = 128, NHID = 64, NCLASS = 40;

typedef unsigned short ushort_t;
typedef int ivec4 __attribute__((ext_vector_type(4)));

__device__ inline ushort_t f2bf(float f) {  // round-to-nearest-even
  union { float f; unsigned int i; } v; v.f = f;
  unsigned int lsb = (v.i >> 16) & 1u;
  v.i += 0x7fffu + lsb;
  return (ushort_t)(v.i >> 16);
}

// Merged: even blocks run the L1 GEMM (S1 = x@W1, 64x64 tile); odd blocks run
// the rank histogram. gemm VALU work fills rank's atomic-latency bubbles.
__global__ __launch_bounds__(256) void rankgemm_k(
    const float* __restrict__ x, const float* __restrict__ W1,
    ushort_t* __restrict__ sout,
    const int* __restrict__ dst, int* __restrict__ cnt4,
    int* __restrict__ rank, int E, int N) {
  constexpr int HS = 68;
  __shared__ float hl[64 * HS];
  __shared__ float wl[64 * 64];
  int tid = threadIdx.x;
  int bid = blockIdx.x;

  if (bid & 1) {
    int i = (bid >> 1) * 256 + tid;
    int base = i * 4;
    if (base >= E) return;
    int4 d4 = *(const int4*)(dst + base);
    int r0 = atomicAdd(&cnt4[0 * N + d4.x], 1);
    int r1 = atomicAdd(&cnt4[1 * N + d4.y], 1);
    int r2 = atomicAdd(&cnt4[2 * N + d4.z], 1);
    int r3 = atomicAdd(&cnt4[3 * N + d4.w], 1);
    ivec4 rr = { (r0 << 2) | 0, (r1 << 2) | 1, (r2 << 2) | 2, (r3 << 2) | 3 };
    __builtin_nontemporal_store(rr, (ivec4*)(rank + base));
    return;
  }

  int row0 = (bid >> 1) * 64;
  int tx = tid & 15, ty = tid >> 4;
  float acc[4][4] = {};
  for (int kc = 0; kc < 128; kc += 64) {
    {
      const float* hb = x + (size_t)row0 * 128 + kc;
      for (int i = tid; i < 64 * 16; i += 256) {
        int r = i >> 4, kk = (i & 15) << 2;
        float4 v = *(const float4*)(hb + (size_t)r * 128 + kk);
        *(float4*)&hl[r * HS + kk] = v;
      }
    }
    {
      const float4* Wb = (const float4*)(W1 + (size_t)kc * 64);
      for (int i = tid; i < 64 * 16; i += 256) ((float4*)wl)[i] = Wb[i];
    }
    __syncthreads();
    for (int k4 = 0; k4 < 64; k4 += 4) {
      float4 a[4];
#pragma unroll
      for (int r = 0; r < 4; ++r)
        a[r] = *(const float4*)&hl[(ty * 4 + r) * HS + k4];
#pragma unroll
      for (int j = 0; j < 4; ++j) {
        float4 bv = *(const float4*)&wl[(k4 + j) * 64 + tx * 4];
        const float* bp = (const float*)&bv;
#pragma unroll
        for (int r = 0; r < 4; ++r) {
          const float* ap = (const float*)&a[r];
#pragma unroll
          for (int c = 0; c < 4; ++c) acc[r][c] += ap[j] * bp[c];
        }
      }
    }
    __syncthreads();
  }
#pragma unroll
  for (int r = 0; r < 4; ++r) {
    ushort_t pk[4];
#pragma unroll
    for (int c = 0; c < 4; ++c) pk[c] = f2bf(acc[r][c]);
    *(ushort4*)&sout[(size_t)(row0 + ty * 4 + r) * 64 + tx * 4] =
        make_ushort4(pk[0], pk[1], pk[2], pk[3]);
  }
}

__global__ void scan1_k(const int* __restrict__ cnt4, int* __restrict__ off,
                        int* __restrict__ bsum, int4* __restrict__ sb4, int n) {
  __shared__ int tmp[256];
  int tid = threadIdx.x;
  int i = blockIdx.x * 256 + tid;
  int c0 = 0, c1 = 0, c2 = 0, c3 = 0;
  if (i < n) {
    c0 = cnt4[i]; c1 = cnt4[n + i]; c2 = cnt4[2 * n + i]; c3 = cnt4[3 * n + i];
  }
  int v = c0 + c1 + c2 + c3;
  tmp[tid] = v;
  __syncthreads();
  for (int d = 1; d < 256; d <<= 1) {
    int t = (tid >= d) ? tmp[tid - d] : 0;
    __syncthreads();
    tmp[tid] += t;
    __syncthreads();
  }
  if (i < n) {
    off[i] = tmp[tid] - v;
    sb4[i] = make_int4(0, c0, c0 + c1, c0 + c1 + c2);
  }
  if (tid == 255) bsum[blockIdx.x] = tmp[255];
}

__global__ void scan2_k(int* __restrict__ bsum, int nb) {
  __shared__ int tmp[256];
  int tid = threadIdx.x;
  int v = (tid < nb) ? bsum[tid] : 0;
  tmp[tid] = v;
  __syncthreads();
  for (int d = 1; d < 256; d <<= 1) {
    int t = (tid >= d) ? tmp[tid - d] : 0;
    __syncthreads();
    tmp[tid] += t;
    __syncthreads();
  }
  if (tid < nb) bsum[tid] = tmp[tid] - v;
}

__global__ void scan3_k(int* __restrict__ off, const int* __restrict__ bsum, int n, int E) {
  int i = blockIdx.x * blockDim.x + threadIdx.x;
  if (i < n) off[i] += bsum[i >> 8];
  if (i == 0) off[n] = E;
}

__global__ void fill_k(const int* __restrict__ src, const int* __restrict__ dst,
                       const float* __restrict__ w, const int* __restrict__ off,
                       const int* __restrict__ rank, const int* __restrict__ sb4,
                       int2* __restrict__ edata, int E) {
  int i = blockIdx.x * blockDim.x + threadIdx.x;
  int base = i * 4;
  if (base >= E) return;
  int4 s4 = *(const int4*)(src + base);
  int4 d4 = *(const int4*)(dst + base);
  float4 w4 = *(const float4*)(w + base);
  int4 r4 = *(const int4*)(rank + base);
  int dd[4] = { d4.x, d4.y, d4.z, d4.w };
  int rr[4] = { r4.x, r4.y, r4.z, r4.w };
  int ss[4] = { s4.x, s4.y, s4.z, s4.w };
  float ww[4] = { w4.x, w4.y, w4.z, w4.w };
  int ob[4], sb[4];
#pragma unroll
  for (int k = 0; k < 4; ++k) ob[k] = off[dd[k]];
#pragma unroll
  for (int k = 0; k < 4; ++k) sb[k] = sb4[dd[k] * 4 + (rr[k] & 3)];
#pragma unroll
  for (int k = 0; k < 4; ++k) {
    int pos = ob[k] + sb[k] + (rr[k] >> 2);
    int2 v = make_int2(ss[k], __float_as_int(ww[k]));
    __builtin_nontemporal_store(*(const long long*)&v, (long long*)&edata[pos]);
  }
}

// Fused pull-aggregate + next-layer GEMM (R11/R14-proven structure).
// Two nodes per wave (A: lanes 0-31, B: lanes 32-63 for edge parity; each
// lane owns feature pair 2hl,2hl+1), flat-issue 2x16 gathers in flight.
// Gather stream order matters (measured): src loads -> gathers -> weight
// loads; merging src+weight into int2 meta regressed 49->64 us (R16).
// GEMM: W staged in LDS; float2 column reads at col2=2*hl (2-way alias, free).
template<int FO, bool WRITE_H>
__global__ __launch_bounds__(256, 4) void aggemm_k(
    const ushort_t* __restrict__ support,   // N x 64 bf16 (layer input S)
    const int2* __restrict__ edata,
    const int* __restrict__ off,
    const float* __restrict__ bias,         // 64
    const float* __restrict__ resid,        // N x 64 f32 or null
    const float* __restrict__ Wn,           // 64 x FO
    ushort_t* __restrict__ sout,            // N x FO bf16 (next layer S)
    float* __restrict__ hout,               // N x 64 f32 (if WRITE_H)
    int n) {
  __shared__ float Wl[64 * FO];
  __shared__ float hls[4][2][64];
  int tid = threadIdx.x;
  for (int i = tid; i < (64 * FO) / 4; i += 256)
    ((float4*)Wl)[i] = ((const float4*)Wn)[i];
  __syncthreads();

  int p = (blockIdx.x * blockDim.x + tid) >> 6, lane = tid & 63;
  int wv = tid >> 6;
  int nA = 2 * p, nB = 2 * p + 1;
  if (nA >= n) return;
  if (nB >= n) nB = n - 1;
  int half = lane >> 5;
  int hl   = lane & 31;
  int e0a = __builtin_amdgcn_readfirstlane(off[nA]);
  int e0b = __builtin_amdgcn_readfirstlane(off[nB]);
  int e1b = __builtin_amdgcn_readfirstlane(off[nB + 1]);
  int degA = e0b - e0a, degB = e1b - e0b;

  const ushort_t* sp = support + hl * 2;
  const int* epA = (const int*)(edata + e0a);
  const int* epB = (const int*)(edata + e0b);

  float axA[4] = {}, ayA[4] = {}, axB[4] = {}, ayB[4] = {};

  // ---- flat gather bodies: A and B issued back-to-back (32 in flight) ----
  int sA[16], sB[16];
#pragma unroll
  for (int j = 0; j < 16; ++j) {
    int rel = 2 * j + half;
    sA[j] = epA[(rel < degA ? rel : 0) * 2];
  }
#pragma unroll
  for (int j = 0; j < 16; ++j) {
    int rel = 2 * j + half;
    sB[j] = epB[(rel < degB ? rel : 0) * 2];
  }
  unsigned int uA[16], uB[16];
#pragma unroll
  for (int j = 0; j < 16; ++j)
    uA[j] = *(const unsigned int*)(sp + ((size_t)sA[j] << 6));
#pragma unroll
  for (int j = 0; j < 16; ++j)
    uB[j] = *(const unsigned int*)(sp + ((size_t)sB[j] << 6));
#pragma unroll
  for (int j = 0; j < 16; ++j) {
    int rel = 2 * j + half;
    float w = (rel < degA) ? __int_as_float(epA[rel * 2 + 1]) : 0.0f;
    axA[j & 3] += w * __int_as_float(uA[j] << 16);
    ayA[j & 3] += w * __int_as_float(uA[j] & 0xffff0000u);
  }
#pragma unroll
  for (int j = 0; j < 16; ++j) {
    int rel = 2 * j + half;
    float w = (rel < degB) ? __int_as_float(epB[rel * 2 + 1]) : 0.0f;
    axB[j & 3] += w * __int_as_float(uB[j] << 16);
    ayB[j & 3] += w * __int_as_float(uB[j] & 0xffff0000u);
  }
  // ---- rare remainder (deg > 32) ----
  for (int it = 32; it < degA; it += 16) {
    int2 ed[8];
#pragma unroll
    for (int j = 0; j < 8; ++j) {
      int rel = it + 2 * j + half;
      ed[j] = *(const int2*)(epA + (rel < degA ? rel : 0) * 2);
    }
    unsigned int uu[8];
#pragma unroll
    for (int j = 0; j < 8; ++j)
      uu[j] = *(const unsigned int*)(sp + ((size_t)ed[j].x << 6));
#pragma unroll
    for (int j = 0; j < 8; ++j) {
      int rel = it + 2 * j + half;
      float w = (rel < degA) ? __int_as_float(ed[j].y) : 0.0f;
      axA[j & 3] += w * __int_as_float(uu[j] << 16);
      ayA[j & 3] += w * __int_as_float(uu[j] & 0xffff0000u);
    }
  }
  for (int it = 32; it < degB; it += 16) {
    int2 ed[8];
#pragma unroll
    for (int j = 0; j < 8; ++j) {
      int rel = it + 2 * j + half;
      ed[j] = *(const int2*)(epB + (rel < degB ? rel : 0) * 2);
    }
    unsigned int uu[8];
#pragma unroll
    for (int j = 0; j < 8; ++j)
      uu[j] = *(const unsigned int*)(sp + ((size_t)ed[j].x << 6));
#pragma unroll
    for (int j = 0; j < 8; ++j) {
      int rel = it + 2 * j + half;
      float w = (rel < degB) ? __int_as_float(ed[j].y) : 0.0f;
      axB[j & 3] += w * __int_as_float(uu[j] << 16);
      ayB[j & 3] += w * __int_as_float(uu[j] & 0xffff0000u);
    }
  }

  float sxA = ((axA[0] + axA[1]) + (axA[2] + axA[3]));
  float syA = ((ayA[0] + ayA[1]) + (ayA[2] + ayA[3]));
  float sxB = ((axB[0] + axB[1]) + (axB[2] + axB[3]));
  float syB = ((ayB[0] + ayB[1]) + (ayB[2] + ayB[3]));
  sxA += __shfl_xor(sxA, 32, 64);
  syA += __shfl_xor(syA, 32, 64);
  sxB += __shfl_xor(sxB, 32, 64);
  syB += __shfl_xor(syB, 32, 64);

  // ---- h epilogue: bias, relu, residual; h -> LDS (+global if needed) ----
  int node = (half == 0) ? nA : nB;
  float2 bv = *(const float2*)&bias[hl * 2];
  float vx = ((half == 0) ? sxA : sxB) + bv.x;
  float vy = ((half == 0) ? syA : syB) + bv.y;
  vx = fmaxf(vx, 0.0f); vy = fmaxf(vy, 0.0f);
  if (resid) {
    float2 r = *(const float2*)&resid[(size_t)node * 64 + hl * 2];
    vx += r.x; vy += r.y;
  }
  if (WRITE_H)
    *(float2*)&hout[(size_t)node * 64 + hl * 2] = make_float2(vx, vy);
  *(float2*)&hls[wv][half][hl * 2] = make_float2(vx, vy);
  __threadfence_block();   // drain ds_write before same-wave cross-lane reads

  // ---- fused GEMM: S_next[node][2hl,2hl+1] = h[node] @ Wn ----
  int col2 = (2 * hl < FO) ? 2 * hl : 0;
  const float* hb = hls[wv][half];
  float ox0 = 0.f, ox1 = 0.f, oy0 = 0.f, oy1 = 0.f;
#pragma unroll
  for (int k = 0; k < 64; k += 4) {
    float4 hv = *(const float4*)&hb[k];   // broadcast within half
    float2 w0 = *(const float2*)&Wl[(k + 0) * FO + col2];
    float2 w1 = *(const float2*)&Wl[(k + 1) * FO + col2];
    float2 w2 = *(const float2*)&Wl[(k + 2) * FO + col2];
    float2 w3 = *(const float2*)&Wl[(k + 3) * FO + col2];
    ox0 += hv.x * w0.x; oy0 += hv.x * w0.y;
    ox1 += hv.y * w1.x; oy1 += hv.y * w1.y;
    ox0 += hv.z * w2.x; oy0 += hv.z * w2.y;
    ox1 += hv.w * w3.x; oy1 += hv.w * w3.y;
  }
  float ox = ox0 + ox1, oy = oy0 + oy1;
  unsigned int pk = (unsigned int)f2bf(ox) | ((unsigned int)f2bf(oy) << 16);
  if (2 * hl < FO)
    *(unsigned int*)&sout[(size_t)node * FO + 2 * hl] = pk;
}

// Final layer: FO=40 aggregation + bias + log_softmax, two nodes per wave.
__global__ __launch_bounds__(256, 4) void agg_final_k(
    const ushort_t* __restrict__ support,
    const int2* __restrict__ edata,
    const int* __restrict__ off,
    const float* __restrict__ bias,
    float* __restrict__ out, int n) {
  int tid = blockIdx.x * blockDim.x + threadIdx.x;
  int p = tid >> 6, lane = tid & 63;
  int nA = 2 * p, nB = 2 * p + 1;
  if (nA >= n) return;
  if (nB >= n) nB = n - 1;
  int half = lane >> 5;
  int hl   = lane & 31;
  int col  = (hl < 20 ? hl : 0) * 2;
  int e0a = __builtin_amdgcn_readfirstlane(off[nA]);
  int e0b = __builtin_amdgcn_readfirstlane(off[nB]);
  int e1b = __builtin_amdgcn_readfirstlane(off[nB + 1]);
  int degA = e0b - e0a, degB = e1b - e0b;

  const ushort_t* sp = support + col;
  const int* epA = (const int*)(edata + e0a);
  const int* epB = (const int*)(edata + e0b);

  float axA[4] = {}, ayA[4] = {}, axB[4] = {}, ayB[4] = {};

  int sA[16], sB[16];
#pragma unroll
  for (int j = 0; j < 16; ++j) {
    int rel = 2 * j + half;
    sA[j] = epA[(rel < degA ? rel : 0) * 2];
  }
#pragma unroll
  for (int j = 0; j < 16; ++j) {
    int rel = 2 * j + half;
    sB[j] = epB[(rel < degB ? rel : 0) * 2];
  }
  unsigned int uA[16], uB[16];
#pragma unroll
  for (int j = 0; j < 16; ++j)
    uA[j] = *(const unsigned int*)(sp + (size_t)sA[j] * NCLASS);
#pragma unroll
  for (int j = 0; j < 16; ++j)
    uB[j] = *(const unsigned int*)(sp + (size_t)sB[j] * NCLASS);
#pragma unroll
  for (int j = 0; j < 16; ++j) {
    int rel = 2 * j + half;
    float w = (rel < degA) ? __int_as_float(epA[rel * 2 + 1]) : 0.0f;
    axA[j & 3] += w * __int_as_float(uA[j] << 16);
    ayA[j & 3] += w * __int_as_float(uA[j] & 0xffff0000u);
  }
#pragma unroll
  for (int j = 0; j < 16; ++j) {
    int rel = 2 * j + half;
    float w = (rel < degB) ? __int_as_float(epB[rel * 2 + 1]) : 0.0f;
    axB[j & 3] += w * __int_as_float(uB[j] << 16);
    ayB[j & 3] += w * __int_as_float(uB[j] & 0xffff0000u);
  }
  for (int it = 32; it < degA; it += 16) {
    int2 ed[8];
#pragma unroll
    for (int j = 0; j < 8; ++j) {
      int rel = it + 2 * j + half;
      ed[j] = *(const int2*)(epA + (rel < degA ? rel : 0) * 2);
    }
    unsigned int uu[8];
#pragma unroll
    for (int j = 0; j < 8; ++j)
      uu[j] = *(const unsigned int*)(sp + (size_t)ed[j].x * NCLASS);
#pragma unroll
    for (int j = 0; j < 8; ++j) {
      int rel = it + 2 * j + half;
      float w = (rel < degA) ? __int_as_float(ed[j].y) : 0.0f;
      axA[j & 3] += w * __int_as_float(uu[j] << 16);
      ayA[j & 3] += w * __int_as_float(uu[j] & 0xffff0000u);
    }
  }
  for (int it = 32; it < degB; it += 16) {
    int2 ed[8];
#pragma unroll
    for (int j = 0; j < 8; ++j) {
      int rel = it + 2 * j + half;
      ed[j] = *(const int2*)(epB + (rel < degB ? rel : 0) * 2);
    }
    unsigned int uu[8];
#pragma unroll
    for (int j = 0; j < 8; ++j)
      uu[j] = *(const unsigned int*)(sp + (size_t)ed[j].x * NCLASS);
#pragma unroll
    for (int j = 0; j < 8; ++j) {
      int rel = it + 2 * j + half;
      float w = (rel < degB) ? __int_as_float(ed[j].y) : 0.0f;
      axB[j & 3] += w * __int_as_float(uu[j] << 16);
      ayB[j & 3] += w * __int_as_float(uu[j] & 0xffff0000u);
    }
  }

  float sxA = ((axA[0] + axA[1]) + (axA[2] + axA[3]));
  float syA = ((ayA[0] + ayA[1]) + (ayA[2] + ayA[3]));
  float sxB = ((axB[0] + axB[1]) + (axB[2] + axB[3]));
  float syB = ((ayB[0] + ayB[1]) + (ayB[2] + ayB[3]));
  sxA += __shfl_xor(sxA, 32, 64);
  syA += __shfl_xor(syA, 32, 64);
  sxB += __shfl_xor(sxB, 32, 64);
  syB += __shfl_xor(syB, 32, 64);

  bool valid = (hl < 20);
  float2 bv = *(const float2*)&bias[col];
  float vxA = sxA + bv.x, vyA = syA + bv.y;
  float vxB = sxB + bv.x, vyB = syB + bv.y;

  float mA2 = valid ? fmaxf(vxA, vyA) : -INFINITY;
  float mB2 = valid ? fmaxf(vxB, vyB) : -INFINITY;
#pragma unroll
  for (int d = 32; d; d >>= 1) {
    mA2 = fmaxf(mA2, __shfl_xor(mA2, d, 64));
    mB2 = fmaxf(mB2, __shfl_xor(mB2, d, 64));
  }
  float exA = (valid && half == 0) ? (expf(vxA - mA2) + expf(vyA - mA2)) : 0.0f;
  float exB = (valid && half == 0) ? (expf(vxB - mB2) + expf(vyB - mB2)) : 0.0f;
  float sA2 = exA, sB2 = exB;
#pragma unroll
  for (int d = 32; d; d >>= 1) {
    sA2 += __shfl_xor(sA2, d, 64);
    sB2 += __shfl_xor(sB2, d, 64);
  }
  if (valid) {
    if (half == 0) {
      float ls = logf(sA2);
      *(float2*)&out[(size_t)nA * NCLASS + hl * 2] =
          make_float2(vxA - mA2 - ls, vyA - mA2 - ls);
    } else {
      float ls = logf(sB2);
      *(float2*)&out[(size_t)nB * NCLASS + hl * 2] =
          make_float2(vxB - mB2 - ls, vyB - mB2 - ls);
    }
  }
}

extern "C" void kernel_launch(void* const* d_in, const int* in_sizes, int n_in,
                              void* d_out, int out_size, void* d_ws, size_t ws_size,
                              hipStream_t stream) {
  const float* x   = (const float*)d_in[0];
  const int*   src = (const int*)d_in[1];
  const int*   dst = (const int*)d_in[2];
  const float* ew  = (const float*)d_in[3];
  const float* W[7]; const float* b[7];
  for (int i = 0; i < 7; ++i) {
    W[i] = (const float*)d_in[4 + 2 * i];
    b[i] = (const float*)d_in[5 + 2 * i];
  }
  int N = in_sizes[0] / NFEAT;   // 65536
  int E = in_sizes[1];           // 1048576

  char* ws = (char*)d_ws;
  int*      off     = (int*)(ws + 0);                 // (N+1) ints
  int*      bsum    = (int*)(ws + (1ll << 20));       // 256 ints
  int*      cnt4    = (int*)(ws + (2ll << 20));       // 4N ints = 1MB
  int4*     sb4     = (int4*)(ws + (3ll << 20));      // N int4 = 1MB
  int2*     edata   = (int2*)(ws + (4ll << 20));      // E int2 = 8MB
  int*      rank    = (int*)(ws + (12ll << 20));      // E ints = 4MB
  ushort_t* SA      = (ushort_t*)(ws + (16ll << 20)); // N*64 bf16 = 8MB
  ushort_t* SB      = (ushort_t*)(ws + (24ll << 20)); // N*64 bf16 = 8MB
  float*    hA      = (float*)(ws + (32ll << 20));    // 16MB
  float*    hB      = (float*)(ws + (48ll << 20));    // 16MB

  // ---- CSR build (rank co-scheduled with L1 GEMM) ----
  (void)hipMemsetAsync(cnt4, 0, (size_t)4 * N * sizeof(int), stream);
  rankgemm_k<<<2048, 256, 0, stream>>>(x, W[0], SA, dst, cnt4, rank, E, N);
  int nb = (N + 255) / 256;
  scan1_k<<<nb, 256, 0, stream>>>(cnt4, off, bsum, sb4, N);
  scan2_k<<<1, 256, 0, stream>>>(bsum, nb);
  scan3_k<<<nb, 256, 0, stream>>>(off, bsum, N, E);
  fill_k<<<(E / 4 + 255) / 256, 256, 0, stream>>>(src, dst, ew, off, rank,
                                                  (const int*)sb4, edata, E);

  int gb_agg = N / 8;   // 2 nodes/wave, 4 waves/block

  // K2: h1 = relu(agg(S1)+b1); S2 = h1@W2
  aggemm_k<64, false><<<gb_agg, 256, 0, stream>>>(SA, edata, off, b[0], nullptr,
                                                  W[1], SB, nullptr, N);
  // K3: h2 = relu(agg(S2)+b2); S3 = h2@W3; keep h2
  aggemm_k<64, true><<<gb_agg, 256, 0, stream>>>(SB, edata, off, b[1], nullptr,
                                                 W[2], SA, hA, N);
  // K4: h3 = relu(agg(S3)+b3)+h2; S4 = h3@W4; keep h3
  aggemm_k<64, true><<<gb_agg, 256, 0, stream>>>(SA, edata, off, b[2], hA,
                                                 W[3], SB, hB, N);
  // K5: h4 = relu(agg(S4)+b4)+h3; S5 = h4@W5; keep h4
  aggemm_k<64, true><<<gb_agg, 256, 0, stream>>>(SB, edata, off, b[3], hB,
                                                 W[4], SA, hA, N);
  // K6: h5 = relu(agg(S5)+b5)+h4; S6 = h5@W6
  aggemm_k<64, false><<<gb_agg, 256, 0, stream>>>(SA, edata, off, b[4], hA,
                                                  W[5], SB, nullptr, N);
  // K7: h6 = relu(agg(S6)+b6); S7 = h6@W7 (64->40)
  aggemm_k<40, false><<<gb_agg, 256, 0, stream>>>(SB, edata, off, b[5], nullptr,
                                                  W[6], SA, nullptr, N);
  // K8: out = log_softmax(agg(S7)+b7)
  agg_final_k<<<gb_agg, 256, 0, stream>>>(SA, edata, off, b[6], (float*)d_out, N);
}